// Round 13
// baseline (593.920 us; speedup 1.0000x reference)
//
#include <hip/hip_runtime.h>
#include <hip/hip_cooperative_groups.h>
#include <hip/hip_bf16.h>
#include <math.h>

namespace cg = cooperative_groups;

#define M 4096
#define ALPHA 0.2f
#define L2E 1.4426950408889634f
#define GRID 512
#define KS 8                                // (M/64)*KS = 512 attn blocks
#define NW 16                               // (M/KS)/32 mask words per row-chunk

typedef __attribute__((ext_vector_type(8))) short bf16x8_t;
typedef __attribute__((ext_vector_type(4))) float f32x4_t;

#define EXP2F(x) __builtin_amdgcn_exp2f(x)

__device__ inline unsigned short f2bf(float f) {      // RNE (cold)
    unsigned int u = __float_as_uint(f);
    u = (u + 0x7fffu + ((u >> 16) & 1u)) >> 16;
    return (unsigned short)u;
}
__device__ inline unsigned short f2bf_fast(float f) { // round-half-up (hot, p>=0)
    return (unsigned short)((__float_as_uint(f) + 0x8000u) >> 16);
}
__device__ inline size_t whb_idx(int i, int c, int NFB) {
    return (((size_t)(i >> 5) * NFB + (c >> 4)) * 64 +
            (((i & 31) >> 3) * 16 + (c & 15))) * 8 + (i & 7);
}

// ---------------- phase: pack one int4 -> packedT bits ----------------
__device__ inline void phase_pack(int g, int lane, const int* __restrict__ adj,
                                  unsigned int* __restrict__ packedT) {
    int4 av = ((const int4*)adj)[g];
    unsigned int nib = (av.x > 0 ? 1u : 0u) | (av.y > 0 ? 2u : 0u) |
                       (av.z > 0 ? 4u : 0u) | (av.w > 0 ? 8u : 0u);
    unsigned int sh = nib << ((lane & 7) * 4);
    sh |= __shfl_xor(sh, 1);
    sh |= __shfl_xor(sh, 2);
    sh |= __shfl_xor(sh, 4);
    if ((lane & 7) == 0) packedT[(size_t)((g >> 3) & 127) * M + (g >> 10)] = sh;
}

// ---------------- phase: Wh1 row + WhB1 scatter + si1/sk1 (one wave per row) ----------
__device__ inline void phase_in(int i, int lane, const float* __restrict__ h0,
                                const float* __restrict__ W1, const float* __restrict__ a1,
                                unsigned short* __restrict__ WhB1,
                                float* __restrict__ si1, float* __restrict__ sk1) {
    float acc = 0.f;
#pragma unroll
    for (int j = 0; j < 64; j++)
        acc += h0[(size_t)i * 64 + j] * W1[j * 64 + lane];
    float vi = acc * a1[lane], vk = acc * a1[64 + lane];
#pragma unroll
    for (int off = 32; off; off >>= 1) { vi += __shfl_xor(vi, off); vk += __shfl_xor(vk, off); }
    if (lane == 0) { si1[i] = vi; sk1[i] = vk; }
    WhB1[whb_idx(i, lane, 4)] = f2bf(acc);
}

// ---------------- phase: attention tile (64 rows x M/KS) ----------------
template <int F>
__device__ void attn_phase(int bid, const unsigned short* __restrict__ WhB,
                           const float* __restrict__ s_i, const float* __restrict__ s_k,
                           const unsigned int* __restrict__ packedT,
                           float* __restrict__ partial, float* __restrict__ partialS,
                           unsigned int (&mask_lds)[64][NW + 1], float (&wred)[4]) {
    constexpr int NFB = F / 16;
    constexpr int NRB = M / 64;
    int tid = threadIdx.x, wave = tid >> 6, lane = tid & 63;
    int rb = bid % NRB, ks = bid / NRB;
    int R0b = rb * 64, k_begin = ks * (M / KS);

    float m = -INFINITY;                               // deterministic global skmax
    for (int j = tid; j < M; j += 256) m = fmaxf(m, s_k[j]);
#pragma unroll
    for (int off = 32; off; off >>= 1) m = fmaxf(m, __shfl_xor(m, off));
    if (lane == 0) wred[wave] = m;
#pragma unroll
    for (int q = 0; q < 4; q++) {                      // stage 64 rows x 16 words
        int lin = q * 256 + tid;
        int st = lin >> 6, r = lin & 63;
        mask_lds[r][st] = packedT[(size_t)(ks * NW + st) * M + R0b + r];
    }
    __syncthreads();
    float skmax = fmaxf(fmaxf(wred[0], wred[1]), fmaxf(wred[2], wred[3]));

    int fl = lane & 15, kg = lane >> 4;
    int R0 = R0b + wave * 16;
    int row = R0 + fl;
    float si = s_i[row];
    float xm = si + skmax;
    float rl2 = fmaxf(xm, ALPHA * xm) * L2E;
    f32x4_t acc[NFB];
#pragma unroll
    for (int fb = 0; fb < NFB; fb++) acc[fb] = (f32x4_t)0.f;
    float rsum = 0.f;
    for (int st = 0; st < NW; st++) {
        int kb = k_begin + st * 32;
        float4 sa = *(const float4*)&s_k[kb + kg * 8];
        float4 sb = *(const float4*)&s_k[kb + kg * 8 + 4];
        unsigned int word = mask_lds[wave * 16 + fl][st];
        float sv[8] = { sa.x, sa.y, sa.z, sa.w, sb.x, sb.y, sb.z, sb.w };
        union { bf16x8_t v; unsigned short u[8]; } af;
#pragma unroll
        for (int j = 0; j < 8; j++) {
            float x = si + sv[j];
            float e = fmaxf(x, ALPHA * x);
            float p = EXP2F(fmaf(e, L2E, -rl2));
            p = ((word >> (kg * 8 + j)) & 1u) ? p : 0.f;
            rsum += p;
            af.u[j] = f2bf_fast(p);
        }
        const unsigned short* bp = WhB + (size_t)(kb >> 5) * (NFB * 512) + (size_t)lane * 8;
#pragma unroll
        for (int fb = 0; fb < NFB; fb++) {
            bf16x8_t bfrag = *(const bf16x8_t*)(bp + (size_t)fb * 512);
            acc[fb] = __builtin_amdgcn_mfma_f32_16x16x32_bf16(af.v, bfrag, acc[fb], 0, 0, 0);
        }
    }
    rsum += __shfl_xor(rsum, 16);
    rsum += __shfl_xor(rsum, 32);
    if (lane < 16) partialS[(size_t)ks * M + R0 + lane] = rsum;
#pragma unroll
    for (int fb = 0; fb < NFB; fb++)
#pragma unroll
        for (int r = 0; r < 4; r++) {
            int ro = R0 + kg * 4 + r;
            partial[((size_t)ks * M + ro) * F + fb * 16 + fl] = acc[fb][r];
        }
}

// ---------------- phase: layer-1 reduce -> h1 -> Wh2/WhB2/si2/sk2 ----------------
__device__ void phase_mid(int i, int wave, int lane, float (&h_lds)[4][64],
                          const float* __restrict__ partial, const float* __restrict__ pS1,
                          const float* __restrict__ W2, const float* __restrict__ a2,
                          unsigned short* __restrict__ WhB2,
                          float* __restrict__ si2, float* __restrict__ sk2) {
    float S = 0.f;
#pragma unroll
    for (int ks = 0; ks < KS; ks++) S += pS1[(size_t)ks * M + i];
    float rinv = S > 0.f ? 1.f / S : 0.f;
    float hv = 0.f;
#pragma unroll
    for (int ks = 0; ks < KS; ks++) hv += partial[((size_t)ks * M + i) * 64 + lane];
    hv *= rinv;
    hv = hv > 0.f ? hv : (__expf(hv) - 1.f);
    h_lds[wave][lane] = hv;
    __syncthreads();
    int g = lane & 31, half = lane >> 5;
    float w2acc = 0.f;
#pragma unroll
    for (int f = 0; f < 32; f++)
        w2acc += h_lds[wave][half * 32 + f] * W2[(half * 32 + f) * 32 + g];
    w2acc += __shfl_xor(w2acc, 32);
    float vi = w2acc * a2[g], vk = w2acc * a2[32 + g];
#pragma unroll
    for (int off = 16; off; off >>= 1) { vi += __shfl_xor(vi, off); vk += __shfl_xor(vk, off); }
    if (lane == 0) { si2[i] = vi; sk2[i] = vk; }
    if (half == 0) WhB2[whb_idx(i, g, 2)] = f2bf(w2acc);
}

// ---------------- phase: layer-2 reduce -> hL write + omega dots ----------------
__device__ void phase_out(int i, int lane, const float* __restrict__ partial,
                          const float* __restrict__ pS2, const float* __restrict__ omega,
                          float* __restrict__ hL_out,
                          float* __restrict__ p_i, float* __restrict__ p_k) {
    int g = lane & 31, half = lane >> 5;
    float S = 0.f;
#pragma unroll
    for (int ks = 0; ks < KS; ks++) S += pS2[(size_t)ks * M + i];
    float rinv = S > 0.f ? 1.f / S : 0.f;
    float hv = 0.f;
#pragma unroll
    for (int h = 0; h < KS / 2; h++) {
        int ks = half * (KS / 2) + h;
        hv += partial[((size_t)ks * M + i) * 32 + g];
    }
    hv += __shfl_xor(hv, 32);
    hv *= rinv;
    hv = hv > 0.f ? hv : (__expf(hv) - 1.f);
    if (half == 0) hL_out[(size_t)i * 32 + g] = hv;
    float vi = hv * omega[g], vk = hv * omega[32 + g];
#pragma unroll
    for (int off = 16; off; off >>= 1) { vi += __shfl_xor(vi, off); vk += __shfl_xor(vk, off); }
    if (lane == 0) { p_i[i] = vi; p_k[i] = vk; }
}

// ---------------- phase: pairwise sigmoid for one float4 ----------------
__device__ inline void phase_pred(int idx4, const float* __restrict__ p_i,
                                  const float* __restrict__ p_k, float* __restrict__ out) {
    int i = idx4 >> 10;
    int k4 = (idx4 & 1023) * 4;
    float pi = p_i[i];
    float4 pk = *(const float4*)&p_k[k4];
    float4 o;
    o.x = 1.f / (1.f + __expf(-(pi + pk.x)));
    o.y = 1.f / (1.f + __expf(-(pi + pk.y)));
    o.z = 1.f / (1.f + __expf(-(pi + pk.z)));
    o.w = 1.f / (1.f + __expf(-(pi + pk.w)));
    *(float4*)&out[(size_t)i * M + k4] = o;
}

// ==================== cooperative mega-kernel (512 blocks, 2/CU) ====================
__global__ __launch_bounds__(256) void mega_kernel(
    const int* __restrict__ adj, const float* __restrict__ h0,
    const float* __restrict__ W1, const float* __restrict__ a1,
    const float* __restrict__ W2, const float* __restrict__ a2,
    const float* __restrict__ omega, float* __restrict__ out,
    unsigned int* __restrict__ packedT,
    unsigned short* __restrict__ WhB1, unsigned short* __restrict__ WhB2,
    float* __restrict__ si1, float* __restrict__ sk1,
    float* __restrict__ si2, float* __restrict__ sk2,
    float* __restrict__ p_i, float* __restrict__ p_k,
    float* __restrict__ pS1, float* __restrict__ pS2) {
    cg::grid_group grid = cg::this_grid();
    __shared__ unsigned int mask_lds[64][NW + 1];
    __shared__ float wred[4];
    __shared__ float h_lds[4][64];
    int tid = threadIdx.x, bid = blockIdx.x;
    int wave = tid >> 6, lane = tid & 63;
    int gid = bid * 256 + tid;
    float* partial = out;
    float* hL_out = out + (size_t)M * M;

    // P0: pack (grid-stride x32)  + P1: layer-1 GEMM/svec (2 row-chunks)
#pragma unroll 4
    for (int t = 0; t < 32; t++) phase_pack(gid + t * (GRID * 256), lane, adj, packedT);
#pragma unroll
    for (int c = 0; c < 2; c++) phase_in(c * 2048 + bid * 4 + wave, lane, h0, W1, a1, WhB1, si1, sk1);
    __threadfence();
    grid.sync();

    // P2: layer-1 attention
    attn_phase<64>(bid, WhB1, si1, sk1, packedT, partial, pS1, mask_lds, wred);
    __threadfence();
    grid.sync();

    // P3: mid (2 row-chunks)
#pragma unroll
    for (int c = 0; c < 2; c++)
        phase_mid(c * 2048 + bid * 4 + wave, wave, lane, h_lds, partial, pS1, W2, a2, WhB2, si2, sk2);
    __threadfence();
    grid.sync();

    // P4: layer-2 attention
    attn_phase<32>(bid, WhB2, si2, sk2, packedT, partial, pS2, mask_lds, wred);
    __threadfence();
    grid.sync();

    // P5: out (2 row-chunks)
#pragma unroll
    for (int c = 0; c < 2; c++)
        phase_out(c * 2048 + bid * 4 + wave, lane, partial, pS2, omega, hL_out, p_i, p_k);
    __threadfence();
    grid.sync();

    // P6: pred (grid-stride x32)
#pragma unroll 4
    for (int t = 0; t < 32; t++) phase_pred(gid + t * (GRID * 256), p_i, p_k, out);
}

// ==================== fallback multi-kernel path (R9-proven) ====================
__global__ __launch_bounds__(256) void pack_kernel(const int* __restrict__ adj,
                                                   unsigned int* __restrict__ packedT) {
    phase_pack(blockIdx.x * 256 + threadIdx.x, threadIdx.x & 63, adj, packedT);
}
__global__ __launch_bounds__(256) void fused_in_kernel(const float* __restrict__ h0,
                                                       const float* __restrict__ W1,
                                                       const float* __restrict__ a1,
                                                       unsigned short* __restrict__ WhB1,
                                                       float* __restrict__ si1,
                                                       float* __restrict__ sk1) {
    phase_in(blockIdx.x * 4 + (threadIdx.x >> 6), threadIdx.x & 63, h0, W1, a1, WhB1, si1, sk1);
}
template <int F>
__global__ __launch_bounds__(256) void attn_kernel(const unsigned short* __restrict__ WhB,
                                                   const float* __restrict__ s_i,
                                                   const float* __restrict__ s_k,
                                                   const unsigned int* __restrict__ packedT,
                                                   float* __restrict__ partial,
                                                   float* __restrict__ partialS) {
    __shared__ unsigned int mask_lds[64][NW + 1];
    __shared__ float wred[4];
    attn_phase<F>(blockIdx.x, WhB, s_i, s_k, packedT, partial, partialS, mask_lds, wred);
}
__global__ __launch_bounds__(256) void mid_kernel(const float* __restrict__ partial,
                                                  const float* __restrict__ pS1,
                                                  const float* __restrict__ W2,
                                                  const float* __restrict__ a2,
                                                  unsigned short* __restrict__ WhB2,
                                                  float* __restrict__ si2,
                                                  float* __restrict__ sk2) {
    __shared__ float h_lds[4][64];
    phase_mid(blockIdx.x * 4 + (threadIdx.x >> 6), threadIdx.x >> 6, threadIdx.x & 63,
              h_lds, partial, pS1, W2, a2, WhB2, si2, sk2);
}
__global__ __launch_bounds__(256) void out_kernel(const float* __restrict__ partial,
                                                  const float* __restrict__ pS2,
                                                  const float* __restrict__ omega,
                                                  float* __restrict__ hL_out,
                                                  float* __restrict__ p_i,
                                                  float* __restrict__ p_k) {
    phase_out(blockIdx.x * 4 + (threadIdx.x >> 6), threadIdx.x & 63,
              partial, pS2, omega, hL_out, p_i, p_k);
}
__global__ __launch_bounds__(256) void pred_kernel(const float* __restrict__ p_i,
                                                   const float* __restrict__ p_k,
                                                   float* __restrict__ out) {
    int gid = blockIdx.x * 256 + threadIdx.x;
#pragma unroll
    for (int t = 0; t < 4; t++) phase_pred(gid + t * (M * M / 16), p_i, p_k, out);
}

extern "C" void kernel_launch(void* const* d_in, const int* in_sizes, int n_in,
                              void* d_out, int out_size, void* d_ws, size_t ws_size,
                              hipStream_t stream) {
    const float* h0    = (const float*)d_in[0];
    const int*   adj   = (const int*)d_in[1];
    const float* W1    = (const float*)d_in[2];
    const float* a1    = (const float*)d_in[3];
    const float* W2    = (const float*)d_in[4];
    const float* a2    = (const float*)d_in[5];
    const float* omega = (const float*)d_in[6];
    float* out = (float*)d_out;

    char* ws = (char*)d_ws;
    unsigned int*   packedT = (unsigned int*)(ws + 0);         // 2 MB
    unsigned short* WhB1    = (unsigned short*)(ws + 2097152); // 512 KB
    unsigned short* WhB2    = (unsigned short*)(ws + 2621440); // 256 KB
    float* si1 = (float*)(ws + 2883584);
    float* sk1 = (float*)(ws + 2899968);
    float* si2 = (float*)(ws + 2916352);
    float* sk2 = (float*)(ws + 2932736);
    float* pi  = (float*)(ws + 2949120);
    float* pk  = (float*)(ws + 2965504);
    float* pS1 = (float*)(ws + 2981888);   // KS*M*4 = 128 KB
    float* pS2 = (float*)(ws + 3112960);   // 128 KB

    void* args[] = { (void*)&adj, (void*)&h0, (void*)&W1, (void*)&a1, (void*)&W2,
                     (void*)&a2, (void*)&omega, (void*)&out, (void*)&packedT,
                     (void*)&WhB1, (void*)&WhB2, (void*)&si1, (void*)&sk1,
                     (void*)&si2, (void*)&sk2, (void*)&pi, (void*)&pk,
                     (void*)&pS1, (void*)&pS2 };
    hipError_t err = hipLaunchCooperativeKernel((void*)mega_kernel, dim3(GRID), dim3(256),
                                                args, 0, stream);
    if (err != hipSuccess) {
        (void)hipGetLastError();                       // clear sticky error
        float* partial = out;
        pack_kernel<<<M * M / 4 / 256, 256, 0, stream>>>(adj, packedT);
        fused_in_kernel<<<M / 4, 256, 0, stream>>>(h0, W1, a1, WhB1, si1, sk1);
        attn_kernel<64><<<(M / 64) * KS, 256, 0, stream>>>(WhB1, si1, sk1, packedT, partial, pS1);
        mid_kernel<<<M / 4, 256, 0, stream>>>(partial, pS1, W2, a2, WhB2, si2, sk2);
        attn_kernel<32><<<(M / 64) * KS, 256, 0, stream>>>(WhB2, si2, sk2, packedT, partial, pS2);
        out_kernel<<<M / 4, 256, 0, stream>>>(partial, pS2, omega, out + (size_t)M * M, pi, pk);
        pred_kernel<<<M * M / 16 / 256, 256, 0, stream>>>(pi, pk, out);
    }
}

// Round 14
// 210.030 us; speedup vs baseline: 2.8278x; 2.8278x over previous
//
#include <hip/hip_runtime.h>
#include <hip/hip_bf16.h>
#include <math.h>

#define M 4096
#define ALPHA 0.2f
#define L2E 1.4426950408889634f
#define KS 8                                // split-K blocks per 64-row group
#define NRB 64                              // M/64 row groups
#define NW 16                               // (M/KS)/32 mask words per K-slice
#define PACK_BLOCKS (M * M / 4 / 256)       // 16384

typedef __attribute__((ext_vector_type(8))) short bf16x8_t;
typedef __attribute__((ext_vector_type(4))) float f32x4_t;

#define EXP2F(x) __builtin_amdgcn_exp2f(x)

__device__ inline unsigned short f2bf(float f) {      // RNE (cold)
    unsigned int u = __float_as_uint(f);
    u = (u + 0x7fffu + ((u >> 16) & 1u)) >> 16;
    return (unsigned short)u;
}
__device__ inline unsigned short f2bf_fast(float f) { // round-half-up (hot, p>=0)
    return (unsigned short)((__float_as_uint(f) + 0x8000u) >> 16);
}
__device__ inline size_t whb_idx(int i, int c, int NFB) {
    return (((size_t)(i >> 5) * NFB + (c >> 4)) * 64 +
            (((i & 31) >> 3) * 16 + (c & 15))) * 8 + (i & 7);
}
// agent-scope load: bypasses the (non-coherent) per-XCD L2 so a fixup block
// can safely read partials written by blocks on other XCDs within one kernel.
__device__ inline float agent_ld(const float* p) {
    return __hip_atomic_load(p, __ATOMIC_RELAXED, __HIP_MEMORY_SCOPE_AGENT);
}

// ================= K1 (fat): pack adj -> packedT || Wh1/WhB1/si1/sk1 || zero flags ======
__global__ __launch_bounds__(256) void prep_fat_kernel(const int* __restrict__ adj,
                                                       unsigned int* __restrict__ packedT,
                                                       const float* __restrict__ h0,
                                                       const float* __restrict__ W1,
                                                       const float* __restrict__ a1,
                                                       unsigned short* __restrict__ WhB1,
                                                       float* __restrict__ si1,
                                                       float* __restrict__ sk1,
                                                       int* __restrict__ flags) {
    int lane = threadIdx.x & 63;
    if (blockIdx.x < PACK_BLOCKS) {
        int g = blockIdx.x * 256 + threadIdx.x;        // int4 index over M*M/4
        int4 av = ((const int4*)adj)[g];
        unsigned int nib = (av.x > 0 ? 1u : 0u) | (av.y > 0 ? 2u : 0u) |
                           (av.z > 0 ? 4u : 0u) | (av.w > 0 ? 8u : 0u);
        unsigned int sh = nib << ((lane & 7) * 4);
        sh |= __shfl_xor(sh, 1);
        sh |= __shfl_xor(sh, 2);
        sh |= __shfl_xor(sh, 4);
        if ((lane & 7) == 0) packedT[(size_t)((g >> 3) & 127) * M + (g >> 10)] = sh;
        return;
    }
    int b = blockIdx.x - PACK_BLOCKS;
    if (b == 0 && threadIdx.x < 2 * NRB) flags[threadIdx.x] = 0;   // reset fixup counters
    int wave = threadIdx.x >> 6;
    int i = b * 4 + wave;
    float acc = 0.f;                                   // Wh1[i][lane]
#pragma unroll
    for (int j = 0; j < 64; j++)
        acc += h0[(size_t)i * 64 + j] * W1[j * 64 + lane];
    float vi = acc * a1[lane], vk = acc * a1[64 + lane];
#pragma unroll
    for (int off = 32; off; off >>= 1) { vi += __shfl_xor(vi, off); vk += __shfl_xor(vk, off); }
    if (lane == 0) { si1[i] = vi; sk1[i] = vk; }
    WhB1[whb_idx(i, lane, 4)] = f2bf(acc);
}

// ============ K2/K3: split-K MFMA attention with last-block fixup epilogue ============
// FINAL=false (F=64): fixup = reduce+norm+ELU -> h1 -> Wh2 -> WhB2/si2/sk2.
// FINAL=true  (F=32): fixup = reduce+norm+ELU -> hL write + omega dots -> p_i/p_k.
template <int F, bool FINAL>
__global__ __launch_bounds__(256) void attn_fix_kernel(const unsigned short* __restrict__ WhB,
                                                       const float* __restrict__ s_i,
                                                       const float* __restrict__ s_k,
                                                       const unsigned int* __restrict__ packedT,
                                                       float* __restrict__ partial,
                                                       float* __restrict__ partialS,
                                                       int* __restrict__ flags,
                                                       const float* __restrict__ W2,
                                                       const float* __restrict__ a2,
                                                       unsigned short* __restrict__ WhB2,
                                                       float* __restrict__ si2,
                                                       float* __restrict__ sk2,
                                                       const float* __restrict__ omega,
                                                       float* __restrict__ hL_out,
                                                       float* __restrict__ p_i,
                                                       float* __restrict__ p_k) {
    constexpr int NFB = F / 16;
    __shared__ unsigned int mask_lds[64][NW + 1];
    __shared__ float wred[4];
    __shared__ float rinv_lds[64];
    __shared__ float h_lds[64][F + 1];
    __shared__ float wh2_lds[FINAL ? 1 : 64][33];
    __shared__ int last_flag;

    int tid = threadIdx.x, wave = tid >> 6, lane = tid & 63;
    int rb = blockIdx.x % NRB, ks = blockIdx.x / NRB;
    int R0b = rb * 64, k_begin = ks * (M / KS);

    // deterministic global skmax (identical in every block)
    float m = -INFINITY;
    for (int j = tid; j < M; j += 256) m = fmaxf(m, s_k[j]);
#pragma unroll
    for (int off = 32; off; off >>= 1) m = fmaxf(m, __shfl_xor(m, off));
    if (lane == 0) wred[wave] = m;
#pragma unroll
    for (int q = 0; q < 4; q++) {                      // stage 64 rows x 16 mask words
        int lin = q * 256 + tid;
        int st = lin >> 6, r = lin & 63;
        mask_lds[r][st] = packedT[(size_t)(ks * NW + st) * M + R0b + r];
    }
    __syncthreads();
    float skmax = fmaxf(fmaxf(wred[0], wred[1]), fmaxf(wred[2], wred[3]));

    int fl = lane & 15, kg = lane >> 4;
    int R0 = R0b + wave * 16;
    int row = R0 + fl;
    float si = s_i[row];
    float xm = si + skmax;
    float rl2 = fmaxf(xm, ALPHA * xm) * L2E;
    f32x4_t acc[NFB];
#pragma unroll
    for (int fb = 0; fb < NFB; fb++) acc[fb] = (f32x4_t)0.f;
    float rsum = 0.f;
    for (int st = 0; st < NW; st++) {
        int kb = k_begin + st * 32;
        float4 sa = *(const float4*)&s_k[kb + kg * 8];
        float4 sb = *(const float4*)&s_k[kb + kg * 8 + 4];
        unsigned int word = mask_lds[wave * 16 + fl][st];
        float sv[8] = { sa.x, sa.y, sa.z, sa.w, sb.x, sb.y, sb.z, sb.w };
        union { bf16x8_t v; unsigned short u[8]; } af;
#pragma unroll
        for (int j = 0; j < 8; j++) {
            float x = si + sv[j];
            float e = fmaxf(x, ALPHA * x);
            float p = EXP2F(fmaf(e, L2E, -rl2));       // unnormalized weight <= 1
            p = ((word >> (kg * 8 + j)) & 1u) ? p : 0.f;
            rsum += p;
            af.u[j] = f2bf_fast(p);
        }
        const unsigned short* bp = WhB + (size_t)(kb >> 5) * (NFB * 512) + (size_t)lane * 8;
#pragma unroll
        for (int fb = 0; fb < NFB; fb++) {
            bf16x8_t bfrag = *(const bf16x8_t*)(bp + (size_t)fb * 512);
            acc[fb] = __builtin_amdgcn_mfma_f32_16x16x32_bf16(af.v, bfrag, acc[fb], 0, 0, 0);
        }
    }
    rsum += __shfl_xor(rsum, 16);
    rsum += __shfl_xor(rsum, 32);
    if (lane < 16) partialS[(size_t)ks * M + R0 + lane] = rsum;
#pragma unroll
    for (int fb = 0; fb < NFB; fb++)
#pragma unroll
        for (int r = 0; r < 4; r++) {
            int ro = R0 + kg * 4 + r;
            partial[((size_t)ks * M + ro) * F + fb * 16 + fl] = acc[fb][r];
        }

    // ---- fixup handshake: last arriving block for this row-group reduces ----
    __threadfence();                                   // flush partial stores (device scope)
    __syncthreads();                                   // all threads' fences done
    if (tid == 0) last_flag = atomicAdd(&flags[rb], 1);
    __syncthreads();
    if (last_flag != KS - 1) return;

    // ---- fixup epilogue (one block per row-group) ----
    if (tid < 64) {
        float S = 0.f;
#pragma unroll
        for (int k2 = 0; k2 < KS; k2++) S += agent_ld(&partialS[(size_t)k2 * M + R0b + tid]);
        rinv_lds[tid] = S > 0.f ? 1.f / S : 0.f;
    }
    __syncthreads();
#pragma unroll
    for (int q = 0; q < (64 * F) / 256; q++) {         // reduce + normalize + ELU
        int cell = q * 256 + tid;
        int r = cell / F, c = cell % F;
        float s = 0.f;
#pragma unroll
        for (int k2 = 0; k2 < KS; k2++)
            s += agent_ld(&partial[((size_t)k2 * M + R0b + r) * F + c]);
        s *= rinv_lds[r];
        s = s > 0.f ? s : (__expf(s) - 1.f);
        h_lds[r][c] = s;
        if (FINAL) hL_out[(size_t)(R0b + r) * F + c] = s;
    }
    __syncthreads();
    if (!FINAL) {
        // Wh2 = h1 @ W2 (64x64 @ 64x32) -> wh2_lds + WhB2 scatter
#pragma unroll
        for (int q = 0; q < 8; q++) {
            int o = q * 256 + tid;
            int r = o >> 5, c = o & 31;
            float acc2 = 0.f;
#pragma unroll
            for (int f = 0; f < 64; f++) acc2 += h_lds[r][f] * W2[f * 32 + c];
            wh2_lds[r][c] = acc2;
            WhB2[whb_idx(R0b + r, c, 2)] = f2bf(acc2);
        }
        __syncthreads();
        if (tid < 64) {
            float vi = 0.f, vk = 0.f;
#pragma unroll
            for (int g = 0; g < 32; g++) {
                float w = wh2_lds[tid][g];
                vi += w * a2[g];
                vk += w * a2[32 + g];
            }
            si2[R0b + tid] = vi;
            sk2[R0b + tid] = vk;
        }
    } else {
        if (tid < 64) {
            float vi = 0.f, vk = 0.f;
#pragma unroll
            for (int g = 0; g < 32; g++) {
                float w = h_lds[tid][g];
                vi += w * omega[g];
                vk += w * omega[32 + g];
            }
            p_i[R0b + tid] = vi;
            p_k[R0b + tid] = vk;
        }
    }
}

// ================= K4: pairwise sigmoid (grid-stride x4) =================
__global__ __launch_bounds__(256) void pred_kernel(const float* __restrict__ p_i,
                                                   const float* __restrict__ p_k,
                                                   float* __restrict__ out) {
    int gid = blockIdx.x * 256 + threadIdx.x;          // 0 .. M*M/16-1
#pragma unroll
    for (int t = 0; t < 4; t++) {
        int idx4 = gid + t * (M * M / 16);
        int i = idx4 >> 10;
        int k4 = (idx4 & 1023) * 4;
        float pi = p_i[i];
        float4 pk = *(const float4*)&p_k[k4];
        float4 o;
        o.x = 1.f / (1.f + __expf(-(pi + pk.x)));
        o.y = 1.f / (1.f + __expf(-(pi + pk.y)));
        o.z = 1.f / (1.f + __expf(-(pi + pk.z)));
        o.w = 1.f / (1.f + __expf(-(pi + pk.w)));
        *(float4*)&out[(size_t)i * M + k4] = o;
    }
}

extern "C" void kernel_launch(void* const* d_in, const int* in_sizes, int n_in,
                              void* d_out, int out_size, void* d_ws, size_t ws_size,
                              hipStream_t stream) {
    const float* h0    = (const float*)d_in[0];
    const int*   adj   = (const int*)d_in[1];
    const float* W1    = (const float*)d_in[2];
    const float* a1    = (const float*)d_in[3];
    const float* W2    = (const float*)d_in[4];
    const float* a2    = (const float*)d_in[5];
    const float* omega = (const float*)d_in[6];
    float* out = (float*)d_out;

    char* ws = (char*)d_ws;
    unsigned int*   packedT = (unsigned int*)(ws + 0);         // 2 MB
    unsigned short* WhB1    = (unsigned short*)(ws + 2097152); // 512 KB
    unsigned short* WhB2    = (unsigned short*)(ws + 2621440); // 256 KB
    float* si1 = (float*)(ws + 2883584);
    float* sk1 = (float*)(ws + 2899968);
    float* si2 = (float*)(ws + 2916352);
    float* sk2 = (float*)(ws + 2932736);
    float* pi  = (float*)(ws + 2949120);
    float* pk  = (float*)(ws + 2965504);
    float* pS1 = (float*)(ws + 2981888);   // KS*M*4 = 128 KB
    float* pS2 = (float*)(ws + 3112960);   // 128 KB
    int*   flags = (int*)(ws + 3244032);   // 2*NRB ints (zeroed each launch in K1)

    float* partial = out;          // d_out as split-K scratch (pred overwrites later)
    float* hL_out  = out + (size_t)M * M;

    // K1: pack (16384 blocks) || layer-1 GEMM/svec (1024 blocks) || flag reset
    prep_fat_kernel<<<PACK_BLOCKS + M / 4, 256, 0, stream>>>(
        adj, packedT, h0, W1, a1, WhB1, si1, sk1, flags);

    // K2: layer-1 attention + last-block mid fixup (-> WhB2, si2, sk2)
    attn_fix_kernel<64, false><<<NRB * KS, 256, 0, stream>>>(
        WhB1, si1, sk1, packedT, partial, pS1, flags,
        W2, a2, WhB2, si2, sk2, nullptr, nullptr, nullptr, nullptr);

    // K3: layer-2 attention + last-block out fixup (-> hL tail, pi, pk)
    attn_fix_kernel<32, true><<<NRB * KS, 256, 0, stream>>>(
        WhB2, si2, sk2, packedT, partial, pS2, flags + NRB,
        nullptr, nullptr, nullptr, nullptr, nullptr, omega, hL_out, pi, pk);

    // K4: pairwise sigmoid
    pred_kernel<<<M * M / 16 / 256, 256, 0, stream>>>(pi, pk, out);
}

// Round 15
// 58.760 us; speedup vs baseline: 10.1076x; 3.5744x over previous
//
#include <hip/hip_runtime.h>
#include <hip/hip_bf16.h>
#include <math.h>

#define M 4096
#define ALPHA 0.2f
#define L2E 1.4426950408889634f
#define PACK_BLOCKS (M * M / 4 / 256)       // 16384

typedef __attribute__((ext_vector_type(8))) short bf16x8_t;
typedef __attribute__((ext_vector_type(4))) float f32x4_t;

#define EXP2F(x) __builtin_amdgcn_exp2f(x)

__device__ inline unsigned short f2bf(float f) {      // RNE (cold)
    unsigned int u = __float_as_uint(f);
    u = (u + 0x7fffu + ((u >> 16) & 1u)) >> 16;
    return (unsigned short)u;
}
__device__ inline unsigned short f2bf_fast(float f) { // round-half-up (hot, p>=0)
    return (unsigned short)((__float_as_uint(f) + 0x8000u) >> 16);
}
__device__ inline size_t whb_idx(int i, int c, int NFB) {
    return (((size_t)(i >> 5) * NFB + (c >> 4)) * 64 +
            (((i & 31) >> 3) * 16 + (c & 15))) * 8 + (i & 7);
}

// ========== K1 (fat): pack adj -> packedT (16384 blocks) || Wh1/WhB1/si1/sk1 ==========
__global__ __launch_bounds__(256) void prep_fat_kernel(const int* __restrict__ adj,
                                                       unsigned int* __restrict__ packedT,
                                                       const float* __restrict__ h0,
                                                       const float* __restrict__ W1,
                                                       const float* __restrict__ a1,
                                                       unsigned short* __restrict__ WhB1,
                                                       float* __restrict__ si1,
                                                       float* __restrict__ sk1) {
    int lane = threadIdx.x & 63;
    if (blockIdx.x < PACK_BLOCKS) {
        int g = blockIdx.x * 256 + threadIdx.x;        // int4 index over M*M/4
        int4 av = ((const int4*)adj)[g];
        unsigned int nib = (av.x > 0 ? 1u : 0u) | (av.y > 0 ? 2u : 0u) |
                           (av.z > 0 ? 4u : 0u) | (av.w > 0 ? 8u : 0u);
        unsigned int sh = nib << ((lane & 7) * 4);
        sh |= __shfl_xor(sh, 1);
        sh |= __shfl_xor(sh, 2);
        sh |= __shfl_xor(sh, 4);
        if ((lane & 7) == 0) packedT[(size_t)((g >> 3) & 127) * M + (g >> 10)] = sh;
        return;
    }
    int wave = threadIdx.x >> 6;
    int i = (blockIdx.x - PACK_BLOCKS) * 4 + wave;
    float acc = 0.f;                                   // Wh1[i][lane]
#pragma unroll
    for (int j = 0; j < 64; j++)
        acc += h0[(size_t)i * 64 + j] * W1[j * 64 + lane];
    float vi = acc * a1[lane], vk = acc * a1[64 + lane];
#pragma unroll
    for (int off = 32; off; off >>= 1) { vi += __shfl_xor(vi, off); vk += __shfl_xor(vk, off); }
    if (lane == 0) { si1[i] = vi; sk1[i] = vk; }
    WhB1[whb_idx(i, lane, 4)] = f2bf(acc);
}

// ========== K2/K3: full-K fused attention, 1024 threads (16 waves, K/16 each) ==========
// Block = 16 rows x full K. Cross-wave reduce in LDS (ordered, deterministic).
// FINAL=false (F=64): epilogue = normalize+ELU -> h1 -> Wh2=h1@W2 -> WhB2/si2/sk2.
// FINAL=true  (F=32): epilogue = normalize+ELU -> hL write + omega dots -> p_i/p_k.
template <int F, bool FINAL>
__global__ __launch_bounds__(1024) void attn_fused_kernel(
    const unsigned short* __restrict__ WhB,
    const float* __restrict__ s_i, const float* __restrict__ s_k,
    const unsigned int* __restrict__ packedT,
    const float* __restrict__ W2, const float* __restrict__ a2,
    unsigned short* __restrict__ WhB2, float* __restrict__ si2, float* __restrict__ sk2,
    const float* __restrict__ omega, float* __restrict__ hL_out,
    float* __restrict__ p_i, float* __restrict__ p_k) {
    constexpr int NFB = F / 16;
    constexpr int NWAVE = 16;
    constexpr int WPW = (M / 32) / NWAVE;              // words per wave = 8
    __shared__ unsigned int mask_lds[16][129];         // 16 rows x 128 words (+pad) 8.25 KB
    __shared__ float acc_lds[NWAVE][16][F + 1];        // 66.6 / 33.8 KB
    __shared__ float sred[NWAVE][16];
    __shared__ float wred[NWAVE];
    __shared__ float h_lds[16][F + 1];

    int tid = threadIdx.x, wave = tid >> 6, lane = tid & 63;
    int R0 = blockIdx.x * 16;

    // deterministic global skmax (identical in every block)
    float m = -INFINITY;
#pragma unroll
    for (int t = 0; t < M / 1024; t++) m = fmaxf(m, s_k[tid + t * 1024]);
#pragma unroll
    for (int off = 32; off; off >>= 1) m = fmaxf(m, __shfl_xor(m, off));
    if (lane == 0) wred[wave] = m;
    // stage mask tile: 16 rows x 128 words
#pragma unroll
    for (int q = 0; q < 2; q++) {
        int lin = q * 1024 + tid;
        int st = lin >> 4, r = lin & 15;
        mask_lds[r][st] = packedT[(size_t)st * M + R0 + r];
    }
    __syncthreads();
    float skmax = wred[0];
#pragma unroll
    for (int w = 1; w < NWAVE; w++) skmax = fmaxf(skmax, wred[w]);

    int fl = lane & 15, kg = lane >> 4;
    int row = R0 + fl;
    float si = s_i[row];
    float xm = si + skmax;
    float rl2 = fmaxf(xm, ALPHA * xm) * L2E;
    f32x4_t acc[NFB];
#pragma unroll
    for (int fb = 0; fb < NFB; fb++) acc[fb] = (f32x4_t)0.f;
    float rsum = 0.f;
    const int kw0 = wave * WPW;
#pragma unroll
    for (int st = 0; st < WPW; st++) {
        int kb = (kw0 + st) * 32;
        float4 sa = *(const float4*)&s_k[kb + kg * 8];
        float4 sb = *(const float4*)&s_k[kb + kg * 8 + 4];
        unsigned int word = mask_lds[fl][kw0 + st];
        float sv[8] = { sa.x, sa.y, sa.z, sa.w, sb.x, sb.y, sb.z, sb.w };
        union { bf16x8_t v; unsigned short u[8]; } af;
#pragma unroll
        for (int j = 0; j < 8; j++) {
            float x = si + sv[j];
            float e = fmaxf(x, ALPHA * x);             // leakyrelu
            float p = EXP2F(fmaf(e, L2E, -rl2));       // unnormalized weight <= 1
            p = ((word >> (kg * 8 + j)) & 1u) ? p : 0.f;
            rsum += p;
            af.u[j] = f2bf_fast(p);
        }
        const unsigned short* bp = WhB + (size_t)(kw0 + st) * (NFB * 512) + (size_t)lane * 8;
#pragma unroll
        for (int fb = 0; fb < NFB; fb++) {
            bf16x8_t bfrag = *(const bf16x8_t*)(bp + (size_t)fb * 512);
            acc[fb] = __builtin_amdgcn_mfma_f32_16x16x32_bf16(af.v, bfrag, acc[fb], 0, 0, 0);
        }
    }
    rsum += __shfl_xor(rsum, 16);
    rsum += __shfl_xor(rsum, 32);
    if (lane < 16) sred[wave][lane] = rsum;
    // spill acc (D layout: col=fl, row=kg*4+r)
#pragma unroll
    for (int fb = 0; fb < NFB; fb++)
#pragma unroll
        for (int r = 0; r < 4; r++)
            acc_lds[wave][kg * 4 + r][fb * 16 + fl] = acc[fb][r];
    __syncthreads();

    // cross-wave reduce + normalize + ELU -> h_lds (one cell per thread)
    if (tid < 16 * F) {
        int r = tid / F, c = tid % F;
        float s = 0.f, S = 0.f;
#pragma unroll
        for (int w = 0; w < NWAVE; w++) { s += acc_lds[w][r][c]; S += sred[w][r]; }
        float h = S > 0.f ? s / S : 0.f;
        h = h > 0.f ? h : (__expf(h) - 1.f);
        h_lds[r][c] = h;
        if (FINAL) hL_out[(size_t)(R0 + r) * F + c] = h;
    }
    __syncthreads();

    // epilogue on 16 complete rows (threads 0..511: r = t>>5, c = t&31)
    if (tid < 512) {
        int r = tid >> 5, c = tid & 31;
        float vi, vk;
        if (!FINAL) {
            float w2 = 0.f;                            // Wh2[r][c] = h1[r] . W2[:,c]
#pragma unroll
            for (int f = 0; f < 64; f++) w2 += h_lds[r][f] * W2[f * 32 + c];
            WhB2[whb_idx(R0 + r, c, 2)] = f2bf(w2);
            vi = w2 * a2[c];
            vk = w2 * a2[32 + c];
        } else {
            float hv = h_lds[r][c];
            vi = hv * omega[c];
            vk = hv * omega[32 + c];
        }
#pragma unroll
        for (int off = 16; off; off >>= 1) { vi += __shfl_xor(vi, off); vk += __shfl_xor(vk, off); }
        if ((tid & 31) == 0) {
            if (!FINAL) { si2[R0 + r] = vi; sk2[R0 + r] = vk; }
            else        { p_i[R0 + r] = vi; p_k[R0 + r] = vk; }
        }
    }
}

// ================= K4: pairwise sigmoid (grid-stride x4) =================
__global__ __launch_bounds__(256) void pred_kernel(const float* __restrict__ p_i,
                                                   const float* __restrict__ p_k,
                                                   float* __restrict__ out) {
    int gid = blockIdx.x * 256 + threadIdx.x;          // 0 .. M*M/16-1
#pragma unroll
    for (int t = 0; t < 4; t++) {
        int idx4 = gid + t * (M * M / 16);
        int i = idx4 >> 10;
        int k4 = (idx4 & 1023) * 4;
        float pi = p_i[i];
        float4 pk = *(const float4*)&p_k[k4];
        float4 o;
        o.x = 1.f / (1.f + __expf(-(pi + pk.x)));
        o.y = 1.f / (1.f + __expf(-(pi + pk.y)));
        o.z = 1.f / (1.f + __expf(-(pi + pk.z)));
        o.w = 1.f / (1.f + __expf(-(pi + pk.w)));
        *(float4*)&out[(size_t)i * M + k4] = o;
    }
}

extern "C" void kernel_launch(void* const* d_in, const int* in_sizes, int n_in,
                              void* d_out, int out_size, void* d_ws, size_t ws_size,
                              hipStream_t stream) {
    const float* h0    = (const float*)d_in[0];
    const int*   adj   = (const int*)d_in[1];
    const float* W1    = (const float*)d_in[2];
    const float* a1    = (const float*)d_in[3];
    const float* W2    = (const float*)d_in[4];
    const float* a2    = (const float*)d_in[5];
    const float* omega = (const float*)d_in[6];
    float* out = (float*)d_out;

    char* ws = (char*)d_ws;
    unsigned int*   packedT = (unsigned int*)(ws + 0);         // 2 MB
    unsigned short* WhB1    = (unsigned short*)(ws + 2097152); // 512 KB
    unsigned short* WhB2    = (unsigned short*)(ws + 2621440); // 256 KB
    float* si1 = (float*)(ws + 2883584);
    float* sk1 = (float*)(ws + 2899968);
    float* si2 = (float*)(ws + 2916352);
    float* sk2 = (float*)(ws + 2932736);
    float* pi  = (float*)(ws + 2949120);
    float* pk  = (float*)(ws + 2965504);

    // K1: pack (16384 blocks) || layer-1 GEMM/svec (1024 blocks)
    prep_fat_kernel<<<PACK_BLOCKS + M / 4, 256, 0, stream>>>(
        adj, packedT, h0, W1, a1, WhB1, si1, sk1);

    // K2: layer-1 full-K attention + mid epilogue (256 blocks x 1024 thr, 16 waves)
    attn_fused_kernel<64, false><<<M / 16, 1024, 0, stream>>>(
        WhB1, si1, sk1, packedT, W2, a2, WhB2, si2, sk2,
        nullptr, nullptr, nullptr, nullptr);

    // K3: layer-2 full-K attention + out epilogue (-> hL tail, pi, pk)
    attn_fused_kernel<32, true><<<M / 16, 1024, 0, stream>>>(
        WhB2, si2, sk2, packedT, nullptr, nullptr, nullptr, nullptr, nullptr,
        omega, out + (size_t)M * M, pi, pk);

    // K4: pairwise sigmoid
    pred_kernel<<<M * M / 16 / 256, 256, 0, stream>>>(pi, pk, out);
}